// Round 1
// baseline (1068.022 us; speedup 1.0000x reference)
//
#include <hip/hip_runtime.h>

#define D_DIM 128
#define EDGE_DIM 32
#define BN_EPS 1e-5f

// ---------------------------------------------------------------------------
// K1: fused edge pass.  msg_e = relu(x[src] + edge_attr[e] @ W_lin + b_lin)
//     agg[dst] += msg_e   (atomic scatter)
// One wave processes 8 edges; lane owns columns {lane, lane+64}.
// eid is wave-uniform -> edge_attr row / indices scalarize to s_loads.
// ---------------------------------------------------------------------------
__global__ __launch_bounds__(256) void edge_msg_kernel(
    const float* __restrict__ x,
    const int*   __restrict__ src_idx,
    const int*   __restrict__ dst_idx,
    const float* __restrict__ ea,
    const float* __restrict__ Wl,
    const float* __restrict__ bl,
    float*       __restrict__ agg,
    int nEdges)
{
    const int lane = threadIdx.x & 63;
    const int wid  = threadIdx.x >> 6;

    // preload this lane's two W_lin columns into registers (64 VGPRs)
    float w0[EDGE_DIM], w1[EDGE_DIM];
#pragma unroll
    for (int k = 0; k < EDGE_DIM; ++k) {
        w0[k] = Wl[k * D_DIM + lane];
        w1[k] = Wl[k * D_DIM + 64 + lane];
    }
    const float b0 = bl[lane];
    const float b1 = bl[64 + lane];

    const int EPW = 8;
    const int e0 = (blockIdx.x * 4 + wid) * EPW;
#pragma unroll 1
    for (int i = 0; i < EPW; ++i) {
        int eid = e0 + i;
        if (eid >= nEdges) return;
        eid = __builtin_amdgcn_readfirstlane(eid);
        const int s = src_idx[eid];
        const int t = dst_idx[eid];
        const float* __restrict__ er = ea + (size_t)eid * EDGE_DIM;
        float a0 = b0, a1 = b1;
#pragma unroll
        for (int k = 0; k < EDGE_DIM; ++k) {
            const float ek = er[k];          // wave-uniform load
            a0 = fmaf(ek, w0[k], a0);
            a1 = fmaf(ek, w1[k], a1);
        }
        const float* __restrict__ xr = x + (size_t)s * D_DIM;
        float m0 = fmaxf(xr[lane]      + a0, 0.f);
        float m1 = fmaxf(xr[64 + lane] + a1, 0.f);
        float* ar = agg + (size_t)t * D_DIM;
        unsafeAtomicAdd(ar + lane,      m0);
        unsafeAtomicAdd(ar + 64 + lane, m1);
    }
}

// ---------------------------------------------------------------------------
// K2/K3: C[M,128] = (A (+ A2)) @ W[128,128] + bias, optional ReLU.
// 64x64 tile, 256 threads, 4x4 microtile, A transposed in LDS.
// ---------------------------------------------------------------------------
template<bool ADD_SRC, bool RELU>
__global__ __launch_bounds__(256) void mlp_gemm_kernel(
    const float* __restrict__ A,
    const float* __restrict__ A2,
    const float* __restrict__ W,
    const float* __restrict__ bias,
    float*       __restrict__ C,
    int M)
{
    constexpr int LDT = 68;                 // padded leading dim (floats)
    __shared__ float AT[64 * LDT];          // AT[k][r]
    __shared__ float WT[64 * LDT];          // WT[k][c]

    const int tid = threadIdx.x;
    const int tx  = tid & 15;               // col quad
    const int ty  = tid >> 4;               // row quad
    const int m0  = blockIdx.x * 64;
    const int c0  = blockIdx.y * 64;

    float acc[4][4];
#pragma unroll
    for (int i = 0; i < 4; ++i)
#pragma unroll
        for (int j = 0; j < 4; ++j) acc[i][j] = 0.f;

    const int lr = tid >> 2;                // 0..63
    const int lq = tid & 3;                 // 0..3

    for (int kk = 0; kk < 2; ++kk) {
        const int k0 = kk * 64;
        // --- stage A tile (transposed), fusing x+agg for K2 ---
        {
            const int  row = m0 + lr;
            const bool ok  = row < M;
#pragma unroll
            for (int s = 0; s < 4; ++s) {
                const int kl = lq * 4 + s * 16;
                float4 av = make_float4(0.f, 0.f, 0.f, 0.f);
                if (ok) {
                    av = *(const float4*)(A + (size_t)row * 128 + k0 + kl);
                    if (ADD_SRC) {
                        const float4 bv = *(const float4*)(A2 + (size_t)row * 128 + k0 + kl);
                        av.x += bv.x; av.y += bv.y; av.z += bv.z; av.w += bv.w;
                    }
                }
                AT[(kl + 0) * LDT + lr] = av.x;
                AT[(kl + 1) * LDT + lr] = av.y;
                AT[(kl + 2) * LDT + lr] = av.z;
                AT[(kl + 3) * LDT + lr] = av.w;
            }
        }
        // --- stage W tile ---
        {
#pragma unroll
            for (int s = 0; s < 4; ++s) {
                const int cl = lq * 4 + s * 16;
                *(float4*)&WT[lr * LDT + cl] =
                    *(const float4*)(W + (size_t)(k0 + lr) * 128 + c0 + cl);
            }
        }
        __syncthreads();
#pragma unroll 8
        for (int k = 0; k < 64; ++k) {
            const float4 a = *(const float4*)&AT[k * LDT + ty * 4];
            const float4 w = *(const float4*)&WT[k * LDT + tx * 4];
            const float aa[4] = {a.x, a.y, a.z, a.w};
            const float ww[4] = {w.x, w.y, w.z, w.w};
#pragma unroll
            for (int i = 0; i < 4; ++i)
#pragma unroll
                for (int j = 0; j < 4; ++j)
                    acc[i][j] = fmaf(aa[i], ww[j], acc[i][j]);
        }
        __syncthreads();
    }

    const int c = c0 + tx * 4;
    const float4 bv = *(const float4*)(bias + c);
    const float bb[4] = {bv.x, bv.y, bv.z, bv.w};
#pragma unroll
    for (int i = 0; i < 4; ++i) {
        const int row = m0 + ty * 4 + i;
        if (row < M) {
            float v0 = acc[i][0] + bb[0];
            float v1 = acc[i][1] + bb[1];
            float v2 = acc[i][2] + bb[2];
            float v3 = acc[i][3] + bb[3];
            if (RELU) {
                v0 = fmaxf(v0, 0.f); v1 = fmaxf(v1, 0.f);
                v2 = fmaxf(v2, 0.f); v3 = fmaxf(v3, 0.f);
            }
            float4 o; o.x = v0; o.y = v1; o.z = v2; o.w = v3;
            *(float4*)(C + (size_t)row * 128 + c) = o;
        }
    }
}

// ---------------------------------------------------------------------------
// K4: per-channel sum / sumsq reduction for BatchNorm (training stats).
// ---------------------------------------------------------------------------
__global__ __launch_bounds__(256) void bn_reduce_kernel(
    const float* __restrict__ h, float* __restrict__ sums, int M)
{
    const int c    = threadIdx.x & 127;
    const int half = threadIdx.x >> 7;
    float s = 0.f, sq = 0.f;
    for (int r = blockIdx.x * 2 + half; r < M; r += gridDim.x * 2) {
        const float v = h[(size_t)r * D_DIM + c];
        s += v; sq += v * v;
    }
    __shared__ float ls[256], lq[256];
    ls[threadIdx.x] = s; lq[threadIdx.x] = sq;
    __syncthreads();
    if (half == 0) {
        s  += ls[threadIdx.x + 128];
        sq += lq[threadIdx.x + 128];
        unsafeAtomicAdd(&sums[c],       s);
        unsafeAtomicAdd(&sums[128 + c], sq);
    }
}

// ---------------------------------------------------------------------------
// K5: BN apply (scale/shift folded) + ReLU, in-place.
// ---------------------------------------------------------------------------
__global__ __launch_bounds__(256) void bn_apply_kernel(
    float* __restrict__ h, const float* __restrict__ sums,
    const float* __restrict__ gamma, const float* __restrict__ beta,
    float invM, int M)
{
    __shared__ float sc[128], sh[128];
    if (threadIdx.x < 128) {
        const int   c   = threadIdx.x;
        const float mu  = sums[c] * invM;
        const float var = sums[128 + c] * invM - mu * mu;
        const float s   = gamma[c] * rsqrtf(var + BN_EPS);
        sc[c] = s;
        sh[c] = beta[c] - mu * s;
    }
    __syncthreads();
    const size_t total = (size_t)M * D_DIM / 4;
    for (size_t i = (size_t)blockIdx.x * 256 + threadIdx.x; i < total;
         i += (size_t)gridDim.x * 256) {
        float4 v = ((const float4*)h)[i];
        const int cb = ((int)(i & 31)) * 4;
        v.x = fmaxf(fmaf(v.x, sc[cb + 0], sh[cb + 0]), 0.f);
        v.y = fmaxf(fmaf(v.y, sc[cb + 1], sh[cb + 1]), 0.f);
        v.z = fmaxf(fmaf(v.z, sc[cb + 2], sh[cb + 2]), 0.f);
        v.w = fmaxf(fmaf(v.w, sc[cb + 3], sh[cb + 3]), 0.f);
        ((float4*)h)[i] = v;
    }
}

// ---------------------------------------------------------------------------
extern "C" void kernel_launch(void* const* d_in, const int* in_sizes, int n_in,
                              void* d_out, int out_size, void* d_ws, size_t ws_size,
                              hipStream_t stream)
{
    const float* x_in  = (const float*)d_in[0];
    const int*   ei    = (const int*)  d_in[1];
    const float* ea    = (const float*)d_in[2];
    const float* W_lin = (const float*)d_in[3];
    const float* b_lin = (const float*)d_in[4];
    const float* W1    = (const float*)d_in[5];
    const float* b1    = (const float*)d_in[6];
    const float* W2    = (const float*)d_in[7];
    const float* b2    = (const float*)d_in[8];
    const float* gamma = (const float*)d_in[9];
    const float* beta  = (const float*)d_in[10];

    const int N = in_sizes[0] / D_DIM;            // 50000
    const int E = in_sizes[2] / EDGE_DIM;         // 600000
    const int L = in_sizes[3] / (EDGE_DIM * D_DIM); // 3

    const int* src = ei;
    const int* dst = ei + E;

    float* out  = (float*)d_out;
    float* agg  = (float*)d_ws;
    float* h1   = agg + (size_t)N * D_DIM;
    float* sums = h1  + (size_t)N * D_DIM;        // 256 floats

    const int edgeBlocks = (E + 31) / 32;         // 32 edges per block
    const int rowBlocks  = (N + 63) / 64;

    for (int l = 0; l < L; ++l) {
        const float* xin = (l == 0) ? x_in : out;
        hipMemsetAsync(agg,  0, (size_t)N * D_DIM * sizeof(float), stream);
        hipMemsetAsync(sums, 0, 256 * sizeof(float), stream);

        edge_msg_kernel<<<edgeBlocks, 256, 0, stream>>>(
            xin, src, dst, ea,
            W_lin + (size_t)l * EDGE_DIM * D_DIM,
            b_lin + (size_t)l * D_DIM, agg, E);

        mlp_gemm_kernel<true, true><<<dim3(rowBlocks, 2), 256, 0, stream>>>(
            xin, agg, W1 + (size_t)l * D_DIM * D_DIM,
            b1 + (size_t)l * D_DIM, h1, N);

        mlp_gemm_kernel<false, false><<<dim3(rowBlocks, 2), 256, 0, stream>>>(
            h1, nullptr, W2 + (size_t)l * D_DIM * D_DIM,
            b2 + (size_t)l * D_DIM, out, N);

        bn_reduce_kernel<<<256, 256, 0, stream>>>(out, sums, N);
        bn_apply_kernel<<<2048, 256, 0, stream>>>(
            out, sums, gamma + (size_t)l * D_DIM, beta + (size_t)l * D_DIM,
            1.f / (float)N, N);
    }
}

// Round 2
// 836.849 us; speedup vs baseline: 1.2762x; 1.2762x over previous
//
#include <hip/hip_runtime.h>

#define D_DIM 128
#define EDGE_DIM 32
#define BN_EPS 1e-5f

// ---------------------------------------------------------------------------
// CSR build: histogram -> single-block scan -> scatter
// ---------------------------------------------------------------------------
__global__ __launch_bounds__(256) void hist_kernel(
    const int* __restrict__ dst, int* __restrict__ cnt, int E)
{
    for (int e = blockIdx.x * 256 + threadIdx.x; e < E; e += gridDim.x * 256)
        atomicAdd(&cnt[dst[e]], 1);
}

__global__ __launch_bounds__(1024) void scan_kernel(
    const int* __restrict__ cnt, int* __restrict__ off,
    int* __restrict__ cur, int n, int chunk)
{
    __shared__ int part[1024];
    const int t = threadIdx.x;
    const int b = t * chunk;
    const int e = min(b + chunk, n);
    int s = 0;
    for (int i = b; i < e; ++i) s += cnt[i];
    part[t] = s;
    __syncthreads();
    for (int d = 1; d < 1024; d <<= 1) {
        const int v = (t >= d) ? part[t - d] : 0;
        __syncthreads();
        part[t] += v;
        __syncthreads();
    }
    int run = (t > 0) ? part[t - 1] : 0;
    for (int i = b; i < e; ++i) {
        off[i] = run;
        cur[i] = run;
        run += cnt[i];
    }
    if (t == 1023) off[n] = run;
}

__global__ __launch_bounds__(256) void scatter_kernel(
    const int* __restrict__ src, const int* __restrict__ dst,
    int* __restrict__ cur, int2* __restrict__ csr, int E)
{
    for (int e = blockIdx.x * 256 + threadIdx.x; e < E; e += gridDim.x * 256) {
        const int p = atomicAdd(&cur[dst[e]], 1);
        csr[p] = make_int2(src[e], e);
    }
}

// ---------------------------------------------------------------------------
// K1': CSR gather-aggregation. One wave per dst node (grid-strided).
//   agg[n] = sum_{e in in(n)} relu(x[src_e] + edge_attr[e] @ W_lin + b_lin)
// Lane owns columns {lane, lane+64}; W_lin columns live in 64 VGPRs.
// No atomics: each agg row written exactly once.
// ---------------------------------------------------------------------------
__global__ __launch_bounds__(256) void edge_agg_csr_kernel(
    const float* __restrict__ x,
    const int2*  __restrict__ csr,
    const int*   __restrict__ row_off,
    const float* __restrict__ ea,
    const float* __restrict__ Wl,
    const float* __restrict__ bl,
    float*       __restrict__ agg,
    int nNodes)
{
    const int lane = threadIdx.x & 63;
    const int wid  = threadIdx.x >> 6;

    float w0[EDGE_DIM], w1[EDGE_DIM];
#pragma unroll
    for (int k = 0; k < EDGE_DIM; ++k) {
        w0[k] = Wl[k * D_DIM + lane];
        w1[k] = Wl[k * D_DIM + 64 + lane];
    }
    const float b0 = bl[lane];
    const float b1 = bl[64 + lane];

    const int stride = gridDim.x * 4;
    for (int node = blockIdx.x * 4 + wid; node < nNodes; node += stride) {
        const int beg = __builtin_amdgcn_readfirstlane(row_off[node]);
        const int end = __builtin_amdgcn_readfirstlane(row_off[node + 1]);
        float acc0 = 0.f, acc1 = 0.f;
#pragma unroll 1
        for (int j = beg; j < end; ++j) {
            const int2 se  = csr[j];
            const int  s   = __builtin_amdgcn_readfirstlane(se.x);
            const int  eid = __builtin_amdgcn_readfirstlane(se.y);
            const float* __restrict__ er = ea + (size_t)eid * EDGE_DIM;
            float a0 = b0, a1 = b1;
#pragma unroll
            for (int k = 0; k < EDGE_DIM; ++k) {
                const float ek = er[k];          // scalar (SGPR-uniform) loads
                a0 = fmaf(ek, w0[k], a0);
                a1 = fmaf(ek, w1[k], a1);
            }
            const float* __restrict__ xr = x + (size_t)s * D_DIM;
            acc0 += fmaxf(xr[lane]      + a0, 0.f);
            acc1 += fmaxf(xr[64 + lane] + a1, 0.f);
        }
        float* ar = agg + (size_t)node * D_DIM;
        ar[lane]      = acc0;
        ar[64 + lane] = acc1;
    }
}

// ---------------------------------------------------------------------------
// K2/K3: C[M,128] = (A (+ A2)) @ W[128,128] + bias, optional ReLU.
// 64x64 tile, 256 threads, 4x4 microtile, A transposed in LDS.
// ---------------------------------------------------------------------------
template<bool ADD_SRC, bool RELU>
__global__ __launch_bounds__(256) void mlp_gemm_kernel(
    const float* __restrict__ A,
    const float* __restrict__ A2,
    const float* __restrict__ W,
    const float* __restrict__ bias,
    float*       __restrict__ C,
    int M)
{
    constexpr int LDT = 68;
    __shared__ float AT[64 * LDT];
    __shared__ float WT[64 * LDT];

    const int tid = threadIdx.x;
    const int tx  = tid & 15;
    const int ty  = tid >> 4;
    const int m0  = blockIdx.x * 64;
    const int c0  = blockIdx.y * 64;

    float acc[4][4];
#pragma unroll
    for (int i = 0; i < 4; ++i)
#pragma unroll
        for (int j = 0; j < 4; ++j) acc[i][j] = 0.f;

    const int lr = tid >> 2;
    const int lq = tid & 3;

    for (int kk = 0; kk < 2; ++kk) {
        const int k0 = kk * 64;
        {
            const int  row = m0 + lr;
            const bool ok  = row < M;
#pragma unroll
            for (int s = 0; s < 4; ++s) {
                const int kl = lq * 4 + s * 16;
                float4 av = make_float4(0.f, 0.f, 0.f, 0.f);
                if (ok) {
                    av = *(const float4*)(A + (size_t)row * 128 + k0 + kl);
                    if (ADD_SRC) {
                        const float4 bv = *(const float4*)(A2 + (size_t)row * 128 + k0 + kl);
                        av.x += bv.x; av.y += bv.y; av.z += bv.z; av.w += bv.w;
                    }
                }
                AT[(kl + 0) * LDT + lr] = av.x;
                AT[(kl + 1) * LDT + lr] = av.y;
                AT[(kl + 2) * LDT + lr] = av.z;
                AT[(kl + 3) * LDT + lr] = av.w;
            }
        }
        {
#pragma unroll
            for (int s = 0; s < 4; ++s) {
                const int cl = lq * 4 + s * 16;
                *(float4*)&WT[lr * LDT + cl] =
                    *(const float4*)(W + (size_t)(k0 + lr) * 128 + c0 + cl);
            }
        }
        __syncthreads();
#pragma unroll 8
        for (int k = 0; k < 64; ++k) {
            const float4 a = *(const float4*)&AT[k * LDT + ty * 4];
            const float4 w = *(const float4*)&WT[k * LDT + tx * 4];
            const float aa[4] = {a.x, a.y, a.z, a.w};
            const float ww[4] = {w.x, w.y, w.z, w.w};
#pragma unroll
            for (int i = 0; i < 4; ++i)
#pragma unroll
                for (int j = 0; j < 4; ++j)
                    acc[i][j] = fmaf(aa[i], ww[j], acc[i][j]);
        }
        __syncthreads();
    }

    const int c = c0 + tx * 4;
    const float4 bv = *(const float4*)(bias + c);
    const float bb[4] = {bv.x, bv.y, bv.z, bv.w};
#pragma unroll
    for (int i = 0; i < 4; ++i) {
        const int row = m0 + ty * 4 + i;
        if (row < M) {
            float v0 = acc[i][0] + bb[0];
            float v1 = acc[i][1] + bb[1];
            float v2 = acc[i][2] + bb[2];
            float v3 = acc[i][3] + bb[3];
            if (RELU) {
                v0 = fmaxf(v0, 0.f); v1 = fmaxf(v1, 0.f);
                v2 = fmaxf(v2, 0.f); v3 = fmaxf(v3, 0.f);
            }
            float4 o; o.x = v0; o.y = v1; o.z = v2; o.w = v3;
            *(float4*)(C + (size_t)row * 128 + c) = o;
        }
    }
}

// ---------------------------------------------------------------------------
// K4: per-channel sum / sumsq reduction for BatchNorm (training stats).
// ---------------------------------------------------------------------------
__global__ __launch_bounds__(256) void bn_reduce_kernel(
    const float* __restrict__ h, float* __restrict__ sums, int M)
{
    const int c    = threadIdx.x & 127;
    const int half = threadIdx.x >> 7;
    float s = 0.f, sq = 0.f;
    for (int r = blockIdx.x * 2 + half; r < M; r += gridDim.x * 2) {
        const float v = h[(size_t)r * D_DIM + c];
        s += v; sq += v * v;
    }
    __shared__ float ls[256], lq[256];
    ls[threadIdx.x] = s; lq[threadIdx.x] = sq;
    __syncthreads();
    if (half == 0) {
        s  += ls[threadIdx.x + 128];
        sq += lq[threadIdx.x + 128];
        unsafeAtomicAdd(&sums[c],       s);
        unsafeAtomicAdd(&sums[128 + c], sq);
    }
}

// ---------------------------------------------------------------------------
// K5: BN apply (scale/shift folded) + ReLU, in-place.
// ---------------------------------------------------------------------------
__global__ __launch_bounds__(256) void bn_apply_kernel(
    float* __restrict__ h, const float* __restrict__ sums,
    const float* __restrict__ gamma, const float* __restrict__ beta,
    float invM, int M)
{
    __shared__ float sc[128], sh[128];
    if (threadIdx.x < 128) {
        const int   c   = threadIdx.x;
        const float mu  = sums[c] * invM;
        const float var = sums[128 + c] * invM - mu * mu;
        const float s   = gamma[c] * rsqrtf(var + BN_EPS);
        sc[c] = s;
        sh[c] = beta[c] - mu * s;
    }
    __syncthreads();
    const size_t total = (size_t)M * D_DIM / 4;
    for (size_t i = (size_t)blockIdx.x * 256 + threadIdx.x; i < total;
         i += (size_t)gridDim.x * 256) {
        float4 v = ((const float4*)h)[i];
        const int cb = ((int)(i & 31)) * 4;
        v.x = fmaxf(fmaf(v.x, sc[cb + 0], sh[cb + 0]), 0.f);
        v.y = fmaxf(fmaf(v.y, sc[cb + 1], sh[cb + 1]), 0.f);
        v.z = fmaxf(fmaf(v.z, sc[cb + 2], sh[cb + 2]), 0.f);
        v.w = fmaxf(fmaf(v.w, sc[cb + 3], sh[cb + 3]), 0.f);
        ((float4*)h)[i] = v;
    }
}

// ---------------------------------------------------------------------------
extern "C" void kernel_launch(void* const* d_in, const int* in_sizes, int n_in,
                              void* d_out, int out_size, void* d_ws, size_t ws_size,
                              hipStream_t stream)
{
    const float* x_in  = (const float*)d_in[0];
    const int*   ei    = (const int*)  d_in[1];
    const float* ea    = (const float*)d_in[2];
    const float* W_lin = (const float*)d_in[3];
    const float* b_lin = (const float*)d_in[4];
    const float* W1    = (const float*)d_in[5];
    const float* b1    = (const float*)d_in[6];
    const float* W2    = (const float*)d_in[7];
    const float* b2    = (const float*)d_in[8];
    const float* gamma = (const float*)d_in[9];
    const float* beta  = (const float*)d_in[10];

    const int N = in_sizes[0] / D_DIM;              // 50000
    const int E = in_sizes[2] / EDGE_DIM;           // 600000
    const int L = in_sizes[3] / (EDGE_DIM * D_DIM); // 3

    const int* src = ei;
    const int* dst = ei + E;

    float* out  = (float*)d_out;

    // ws layout
    float* agg  = (float*)d_ws;                       // N*128 f
    float* h1   = agg + (size_t)N * D_DIM;            // N*128 f
    float* sums = h1  + (size_t)N * D_DIM;            // 256 f
    int*   cnt     = (int*)(sums + 256);              // N
    int*   row_off = cnt + N;                         // N+1
    int*   cur     = row_off + (N + 1);               // N
    int2*  csr     = (int2*)(((uintptr_t)(cur + N) + 15) & ~(uintptr_t)15); // E int2

    const int rowBlocks = (N + 63) / 64;

    // ---- CSR build (once per call; reused by all 3 layers) ----
    hipMemsetAsync(cnt, 0, (size_t)N * sizeof(int), stream);
    hist_kernel<<<1024, 256, 0, stream>>>(dst, cnt, E);
    scan_kernel<<<1, 1024, 0, stream>>>(cnt, row_off, cur, N, (N + 1023) / 1024);
    scatter_kernel<<<1024, 256, 0, stream>>>(src, dst, cur, csr, E);

    for (int l = 0; l < L; ++l) {
        const float* xin = (l == 0) ? x_in : out;
        hipMemsetAsync(sums, 0, 256 * sizeof(float), stream);

        edge_agg_csr_kernel<<<2048, 256, 0, stream>>>(
            xin, csr, row_off, ea,
            W_lin + (size_t)l * EDGE_DIM * D_DIM,
            b_lin + (size_t)l * D_DIM, agg, N);

        mlp_gemm_kernel<true, true><<<dim3(rowBlocks, 2), 256, 0, stream>>>(
            xin, agg, W1 + (size_t)l * D_DIM * D_DIM,
            b1 + (size_t)l * D_DIM, h1, N);

        mlp_gemm_kernel<false, false><<<dim3(rowBlocks, 2), 256, 0, stream>>>(
            h1, nullptr, W2 + (size_t)l * D_DIM * D_DIM,
            b2 + (size_t)l * D_DIM, out, N);

        bn_reduce_kernel<<<256, 256, 0, stream>>>(out, sums, N);
        bn_apply_kernel<<<2048, 256, 0, stream>>>(
            out, sums, gamma + (size_t)l * D_DIM, beta + (size_t)l * D_DIM,
            1.f / (float)N, N);
    }
}

// Round 3
// 645.545 us; speedup vs baseline: 1.6545x; 1.2963x over previous
//
#include <hip/hip_runtime.h>

#define D_DIM 128
#define EDGE_DIM 32
#define BN_EPS 1e-5f

typedef __attribute__((ext_vector_type(8))) short bf16x8;
typedef __attribute__((ext_vector_type(4))) float f32x4;

__device__ __forceinline__ unsigned short f2bf(float f) {
    unsigned u = __float_as_uint(f);
    return (unsigned short)((u + 0x7FFFu + ((u >> 16) & 1u)) >> 16);
}
__device__ __forceinline__ unsigned pk2(float lo, float hi) {
    return (unsigned)f2bf(lo) | ((unsigned)f2bf(hi) << 16);
}

// ---------------------------------------------------------------------------
// CSR build: histogram -> single-block scan -> scatter
// ---------------------------------------------------------------------------
__global__ __launch_bounds__(256) void hist_kernel(
    const int* __restrict__ dst, int* __restrict__ cnt, int E)
{
    for (int e = blockIdx.x * 256 + threadIdx.x; e < E; e += gridDim.x * 256)
        atomicAdd(&cnt[dst[e]], 1);
}

__global__ __launch_bounds__(1024) void scan_kernel(
    const int* __restrict__ cnt, int* __restrict__ off,
    int* __restrict__ cur, int n, int chunk)
{
    __shared__ int part[1024];
    const int t = threadIdx.x;
    const int b = t * chunk;
    const int e = min(b + chunk, n);
    int s = 0;
    for (int i = b; i < e; ++i) s += cnt[i];
    part[t] = s;
    __syncthreads();
    for (int d = 1; d < 1024; d <<= 1) {
        const int v = (t >= d) ? part[t - d] : 0;
        __syncthreads();
        part[t] += v;
        __syncthreads();
    }
    int run = (t > 0) ? part[t - 1] : 0;
    for (int i = b; i < e; ++i) {
        off[i] = run;
        cur[i] = run;
        run += cnt[i];
    }
    if (t == 1023) off[n] = run;
}

__global__ __launch_bounds__(256) void scatter_kernel(
    const int* __restrict__ src, const int* __restrict__ dst,
    int* __restrict__ cur, int2* __restrict__ csr, int E)
{
    for (int e = blockIdx.x * 256 + threadIdx.x; e < E; e += gridDim.x * 256) {
        const int p = atomicAdd(&cur[dst[e]], 1);
        csr[p] = make_int2(src[e], e);
    }
}

// ---------------------------------------------------------------------------
// Edge aggregation over CSR, one wave per node, unrolled x2 for ILP.
// Optionally applies x' = relu(x*sc + sh) (previous layer's BN) on the fly.
// ---------------------------------------------------------------------------
template<int XFORM>
__global__ __launch_bounds__(256) void edge_agg_csr_kernel(
    const float* __restrict__ x,
    const int2*  __restrict__ csr,
    const int*   __restrict__ row_off,
    const float* __restrict__ ea,
    const float* __restrict__ Wl,
    const float* __restrict__ bl,
    const float* __restrict__ scsh,
    float*       __restrict__ agg,
    int nNodes)
{
    const int lane = threadIdx.x & 63;
    const int wid  = threadIdx.x >> 6;

    float w0[EDGE_DIM], w1[EDGE_DIM];
#pragma unroll
    for (int k = 0; k < EDGE_DIM; ++k) {
        w0[k] = Wl[k * D_DIM + lane];
        w1[k] = Wl[k * D_DIM + 64 + lane];
    }
    const float b0 = bl[lane];
    const float b1 = bl[64 + lane];

    float scl0 = 1.f, shl0 = 0.f, scl1 = 1.f, shl1 = 0.f;
    if (XFORM) {
        scl0 = scsh[lane];      shl0 = scsh[128 + lane];
        scl1 = scsh[64 + lane]; shl1 = scsh[192 + lane];
    }

    const int stride = gridDim.x * 4;
    for (int node = blockIdx.x * 4 + wid; node < nNodes; node += stride) {
        const int beg = __builtin_amdgcn_readfirstlane(row_off[node]);
        const int end = __builtin_amdgcn_readfirstlane(row_off[node + 1]);
        float acc0 = 0.f, acc1 = 0.f;
        int j = beg;
        if ((end - beg) & 1) {
            const int2 se  = csr[j];
            const int  s0  = __builtin_amdgcn_readfirstlane(se.x);
            const int  e0  = __builtin_amdgcn_readfirstlane(se.y);
            const float* __restrict__ er = ea + (size_t)e0 * EDGE_DIM;
            const float* __restrict__ xr = x + (size_t)s0 * D_DIM;
            float xa = xr[lane], xb = xr[64 + lane];
            if (XFORM) {
                xa = fmaxf(fmaf(xa, scl0, shl0), 0.f);
                xb = fmaxf(fmaf(xb, scl1, shl1), 0.f);
            }
            float p0 = b0, p1 = b1;
#pragma unroll
            for (int k = 0; k < EDGE_DIM; ++k) {
                const float ek = er[k];
                p0 = fmaf(ek, w0[k], p0);
                p1 = fmaf(ek, w1[k], p1);
            }
            acc0 += fmaxf(xa + p0, 0.f);
            acc1 += fmaxf(xb + p1, 0.f);
            ++j;
        }
#pragma unroll 1
        for (; j < end; j += 2) {
            const int2 seA = csr[j];
            const int2 seB = csr[j + 1];
            const int sA = __builtin_amdgcn_readfirstlane(seA.x);
            const int eA = __builtin_amdgcn_readfirstlane(seA.y);
            const int sB = __builtin_amdgcn_readfirstlane(seB.x);
            const int eB = __builtin_amdgcn_readfirstlane(seB.y);
            const float* __restrict__ xrA = x + (size_t)sA * D_DIM;
            const float* __restrict__ xrB = x + (size_t)sB * D_DIM;
            float xa = xrA[lane], xb = xrA[64 + lane];
            float xc = xrB[lane], xd = xrB[64 + lane];
            if (XFORM) {
                xa = fmaxf(fmaf(xa, scl0, shl0), 0.f);
                xb = fmaxf(fmaf(xb, scl1, shl1), 0.f);
                xc = fmaxf(fmaf(xc, scl0, shl0), 0.f);
                xd = fmaxf(fmaf(xd, scl1, shl1), 0.f);
            }
            const float* __restrict__ erA = ea + (size_t)eA * EDGE_DIM;
            const float* __restrict__ erB = ea + (size_t)eB * EDGE_DIM;
            float p0 = b0, p1 = b1, q0 = b0, q1 = b1;
#pragma unroll
            for (int k = 0; k < EDGE_DIM; ++k) {
                const float ekA = erA[k];
                const float ekB = erB[k];
                p0 = fmaf(ekA, w0[k], p0);
                p1 = fmaf(ekA, w1[k], p1);
                q0 = fmaf(ekB, w0[k], q0);
                q1 = fmaf(ekB, w1[k], q1);
            }
            acc0 += fmaxf(xa + p0, 0.f) + fmaxf(xc + q0, 0.f);
            acc1 += fmaxf(xb + p1, 0.f) + fmaxf(xd + q1, 0.f);
        }
        float* ar = agg + (size_t)node * D_DIM;
        ar[lane]      = acc0;
        ar[64 + lane] = acc1;
    }
}

// ---------------------------------------------------------------------------
// MFMA GEMM 1: h1 = relu( (xform(x) + agg) @ W1 + b1 )  -> bf16 output
// BM=128 rows/block, N=K=128. LDS tiles XOR-swizzled (byte ^= (row&7)<<4).
// ---------------------------------------------------------------------------
template<int XFORM>
__global__ __launch_bounds__(256) void gemm1_kernel(
    const float* __restrict__ A,
    const float* __restrict__ agg,
    const float* __restrict__ W,
    const float* __restrict__ bias,
    const float* __restrict__ scsh,
    unsigned short* __restrict__ h1,
    int M)
{
    __shared__ char ATb[128 * 256];
    __shared__ char WTb[128 * 256];
    const int tid = threadIdx.x;
    const int m0  = blockIdx.x * 128;

    // stage A (fp32 -> bf16), fused transform + agg add
#pragma unroll
    for (int i = 0; i < 16; ++i) {
        const int idx = i * 256 + tid;
        const int r = idx >> 5, c4 = idx & 31;
        const int row = m0 + r;
        f32x4 v = {0.f, 0.f, 0.f, 0.f};
        if (row < M) {
            v = *(const f32x4*)(A + (size_t)row * 128 + c4 * 4);
            if (XFORM) {
                const f32x4 s4 = *(const f32x4*)(scsh + c4 * 4);
                const f32x4 h4 = *(const f32x4*)(scsh + 128 + c4 * 4);
#pragma unroll
                for (int j = 0; j < 4; ++j)
                    v[j] = fmaxf(fmaf(v[j], s4[j], h4[j]), 0.f);
            }
            const f32x4 g = *(const f32x4*)(agg + (size_t)row * 128 + c4 * 4);
            v += g;
        }
        uint2 p; p.x = pk2(v[0], v[1]); p.y = pk2(v[2], v[3]);
        *(uint2*)(ATb + r * 256 + ((c4 * 8) ^ ((r & 7) << 4))) = p;
    }
    // stage W transposed (WT[col][k], bf16, k-pairs packed)
#pragma unroll
    for (int i = 0; i < 8; ++i) {
        const int c4 = (tid >> 6) + 4 * i;
        const int kp = tid & 63;
        const f32x4 wa = *(const f32x4*)(W + (size_t)(2 * kp) * 128 + c4 * 4);
        const f32x4 wb = *(const f32x4*)(W + (size_t)(2 * kp + 1) * 128 + c4 * 4);
#pragma unroll
        for (int j = 0; j < 4; ++j) {
            const int col = c4 * 4 + j;
            *(unsigned*)(WTb + col * 256 + ((kp * 4) ^ ((col & 7) << 4))) = pk2(wa[j], wb[j]);
        }
    }
    __syncthreads();

    const int lane = tid & 63;
    const int w    = tid >> 6;
    const int fr   = lane & 15;
    const int fg   = lane >> 4;

    f32x4 acc[2][8];
#pragma unroll
    for (int a = 0; a < 2; ++a)
#pragma unroll
        for (int b = 0; b < 8; ++b) acc[a][b] = (f32x4){0.f, 0.f, 0.f, 0.f};

    const int ar0 = w * 32 + fr;
    const int asz = (ar0 & 7) << 4;
#pragma unroll
    for (int ks = 0; ks < 4; ++ks) {
        const int kb = ks * 64 + fg * 16;
        const bf16x8 a0 = *(const bf16x8*)(ATb + ar0 * 256 + (kb ^ asz));
        const bf16x8 a1 = *(const bf16x8*)(ATb + (ar0 + 16) * 256 + (kb ^ asz));
#pragma unroll
        for (int cb = 0; cb < 8; ++cb) {
            const int col = cb * 16 + fr;
            const bf16x8 b = *(const bf16x8*)(WTb + col * 256 + (kb ^ ((col & 7) << 4)));
            acc[0][cb] = __builtin_amdgcn_mfma_f32_16x16x32_bf16(a0, b, acc[0][cb], 0, 0, 0);
            acc[1][cb] = __builtin_amdgcn_mfma_f32_16x16x32_bf16(a1, b, acc[1][cb], 0, 0, 0);
        }
    }

    float bv[8];
#pragma unroll
    for (int cb = 0; cb < 8; ++cb) bv[cb] = bias[cb * 16 + fr];
#pragma unroll
    for (int rf = 0; rf < 2; ++rf) {
        const int r0 = m0 + w * 32 + rf * 16 + fg * 4;
#pragma unroll
        for (int cb = 0; cb < 8; ++cb) {
            const int col = cb * 16 + fr;
#pragma unroll
            for (int j = 0; j < 4; ++j) {
                const int row = r0 + j;
                if (row < M) {
                    const float v = fmaxf(acc[rf][cb][j] + bv[cb], 0.f);
                    h1[(size_t)row * 128 + col] = f2bf(v);
                }
            }
        }
    }
}

// ---------------------------------------------------------------------------
// MFMA GEMM 2: h = h1 @ W2 + b2 (fp32 out) + fused BN column sums/sumsq.
// ---------------------------------------------------------------------------
__global__ __launch_bounds__(256) void gemm2_kernel(
    const unsigned short* __restrict__ h1,
    const float* __restrict__ W,
    const float* __restrict__ bias,
    float* __restrict__ C,
    float* __restrict__ sums,
    int M)
{
    __shared__ char ATb[128 * 256];
    __shared__ char WTb[128 * 256];
    __shared__ float bsum[256];
    const int tid = threadIdx.x;
    const int m0  = blockIdx.x * 128;

    bsum[tid] = 0.f;

    // stage A (already bf16)
#pragma unroll
    for (int i = 0; i < 8; ++i) {
        const int idx = i * 256 + tid;
        const int r = idx >> 4, c8 = idx & 15;
        const int row = m0 + r;
        uint4 v = make_uint4(0u, 0u, 0u, 0u);
        if (row < M) v = *(const uint4*)(h1 + (size_t)row * 128 + c8 * 8);
        *(uint4*)(ATb + r * 256 + ((c8 * 16) ^ ((r & 7) << 4))) = v;
    }
#pragma unroll
    for (int i = 0; i < 8; ++i) {
        const int c4 = (tid >> 6) + 4 * i;
        const int kp = tid & 63;
        const f32x4 wa = *(const f32x4*)(W + (size_t)(2 * kp) * 128 + c4 * 4);
        const f32x4 wb = *(const f32x4*)(W + (size_t)(2 * kp + 1) * 128 + c4 * 4);
#pragma unroll
        for (int j = 0; j < 4; ++j) {
            const int col = c4 * 4 + j;
            *(unsigned*)(WTb + col * 256 + ((kp * 4) ^ ((col & 7) << 4))) = pk2(wa[j], wb[j]);
        }
    }
    __syncthreads();

    const int lane = tid & 63;
    const int w    = tid >> 6;
    const int fr   = lane & 15;
    const int fg   = lane >> 4;

    f32x4 acc[2][8];
#pragma unroll
    for (int a = 0; a < 2; ++a)
#pragma unroll
        for (int b = 0; b < 8; ++b) acc[a][b] = (f32x4){0.f, 0.f, 0.f, 0.f};

    const int ar0 = w * 32 + fr;
    const int asz = (ar0 & 7) << 4;
#pragma unroll
    for (int ks = 0; ks < 4; ++ks) {
        const int kb = ks * 64 + fg * 16;
        const bf16x8 a0 = *(const bf16x8*)(ATb + ar0 * 256 + (kb ^ asz));
        const bf16x8 a1 = *(const bf16x8*)(ATb + (ar0 + 16) * 256 + (kb ^ asz));
#pragma unroll
        for (int cb = 0; cb < 8; ++cb) {
            const int col = cb * 16 + fr;
            const bf16x8 b = *(const bf16x8*)(WTb + col * 256 + (kb ^ ((col & 7) << 4)));
            acc[0][cb] = __builtin_amdgcn_mfma_f32_16x16x32_bf16(a0, b, acc[0][cb], 0, 0, 0);
            acc[1][cb] = __builtin_amdgcn_mfma_f32_16x16x32_bf16(a1, b, acc[1][cb], 0, 0, 0);
        }
    }

    float bv[8];
#pragma unroll
    for (int cb = 0; cb < 8; ++cb) bv[cb] = bias[cb * 16 + fr];
    float s[8], q[8];
#pragma unroll
    for (int cb = 0; cb < 8; ++cb) { s[cb] = 0.f; q[cb] = 0.f; }

#pragma unroll
    for (int rf = 0; rf < 2; ++rf) {
        const int r0 = m0 + w * 32 + rf * 16 + fg * 4;
#pragma unroll
        for (int cb = 0; cb < 8; ++cb) {
            const int col = cb * 16 + fr;
#pragma unroll
            for (int j = 0; j < 4; ++j) {
                const int row = r0 + j;
                if (row < M) {
                    const float v = acc[rf][cb][j] + bv[cb];
                    C[(size_t)row * 128 + col] = v;
                    s[cb] += v;
                    q[cb] += v * v;
                }
            }
        }
    }
#pragma unroll
    for (int cb = 0; cb < 8; ++cb) {
        float ss = s[cb]; ss += __shfl_down(ss, 32); ss += __shfl_down(ss, 16);
        float qq = q[cb]; qq += __shfl_down(qq, 32); qq += __shfl_down(qq, 16);
        if (lane < 16) {
            atomicAdd(&bsum[cb * 16 + lane], ss);
            atomicAdd(&bsum[128 + cb * 16 + lane], qq);
        }
    }
    __syncthreads();
    unsafeAtomicAdd(&sums[tid], bsum[tid]);
}

// ---------------------------------------------------------------------------
// BN finalize: sums -> scale/shift
// ---------------------------------------------------------------------------
__global__ __launch_bounds__(128) void bn_finalize_kernel(
    const float* __restrict__ sums,
    const float* __restrict__ gamma, const float* __restrict__ beta,
    float* __restrict__ scsh, float invM)
{
    const int c = threadIdx.x;
    const float mu  = sums[c] * invM;
    const float var = sums[128 + c] * invM - mu * mu;
    const float sc  = gamma[c] * rsqrtf(var + BN_EPS);
    scsh[c]       = sc;
    scsh[128 + c] = beta[c] - mu * sc;
}

// ---------------------------------------------------------------------------
// Final BN apply + ReLU in-place (last layer only).
// ---------------------------------------------------------------------------
__global__ __launch_bounds__(256) void bn_apply_final(
    float* __restrict__ h, const float* __restrict__ scsh, int M)
{
    __shared__ float sc[128], sh[128];
    if (threadIdx.x < 128) {
        sc[threadIdx.x] = scsh[threadIdx.x];
        sh[threadIdx.x] = scsh[128 + threadIdx.x];
    }
    __syncthreads();
    const size_t total = (size_t)M * D_DIM / 4;
    for (size_t i = (size_t)blockIdx.x * 256 + threadIdx.x; i < total;
         i += (size_t)gridDim.x * 256) {
        float4 v = ((const float4*)h)[i];
        const int cb = ((int)(i & 31)) * 4;
        v.x = fmaxf(fmaf(v.x, sc[cb + 0], sh[cb + 0]), 0.f);
        v.y = fmaxf(fmaf(v.y, sc[cb + 1], sh[cb + 1]), 0.f);
        v.z = fmaxf(fmaf(v.z, sc[cb + 2], sh[cb + 2]), 0.f);
        v.w = fmaxf(fmaf(v.w, sc[cb + 3], sh[cb + 3]), 0.f);
        ((float4*)h)[i] = v;
    }
}

// ---------------------------------------------------------------------------
extern "C" void kernel_launch(void* const* d_in, const int* in_sizes, int n_in,
                              void* d_out, int out_size, void* d_ws, size_t ws_size,
                              hipStream_t stream)
{
    const float* x_in  = (const float*)d_in[0];
    const int*   ei    = (const int*)  d_in[1];
    const float* ea    = (const float*)d_in[2];
    const float* W_lin = (const float*)d_in[3];
    const float* b_lin = (const float*)d_in[4];
    const float* W1    = (const float*)d_in[5];
    const float* b1    = (const float*)d_in[6];
    const float* W2    = (const float*)d_in[7];
    const float* b2    = (const float*)d_in[8];
    const float* gamma = (const float*)d_in[9];
    const float* beta  = (const float*)d_in[10];

    const int N = in_sizes[0] / D_DIM;              // 50000
    const int E = in_sizes[2] / EDGE_DIM;           // 600000
    const int L = in_sizes[3] / (EDGE_DIM * D_DIM); // 3

    const int* src = ei;
    const int* dst = ei + E;

    float* out = (float*)d_out;

    // ws layout
    char* wp = (char*)d_ws;
    float* agg = (float*)wp;                 wp += (size_t)N * D_DIM * 4;
    unsigned short* h1 = (unsigned short*)wp; wp += (size_t)N * D_DIM * 2;
    float* sums = (float*)wp;                wp += 256 * 4;
    float* scsh = (float*)wp;                wp += 256 * 4;
    int* cnt     = (int*)wp;                 wp += (size_t)N * 4;
    int* row_off = (int*)wp;                 wp += (size_t)(N + 1) * 4;
    int* cur     = (int*)wp;                 wp += (size_t)N * 4;
    wp = (char*)(((uintptr_t)wp + 15) & ~(uintptr_t)15);
    int2* csr = (int2*)wp;

    const int gemmBlocks = (N + 127) / 128;

    // ---- CSR build (edge_index fixed across layers) ----
    hipMemsetAsync(cnt, 0, (size_t)N * sizeof(int), stream);
    hist_kernel<<<1024, 256, 0, stream>>>(dst, cnt, E);
    scan_kernel<<<1, 1024, 0, stream>>>(cnt, row_off, cur, N, (N + 1023) / 1024);
    scatter_kernel<<<1024, 256, 0, stream>>>(src, dst, cur, csr, E);

    for (int l = 0; l < L; ++l) {
        const float* xin = (l == 0) ? x_in : out;
        hipMemsetAsync(sums, 0, 256 * sizeof(float), stream);

        const float* Wl_l = W_lin + (size_t)l * EDGE_DIM * D_DIM;
        const float* bl_l = b_lin + (size_t)l * D_DIM;
        const float* W1_l = W1 + (size_t)l * D_DIM * D_DIM;
        const float* b1_l = b1 + (size_t)l * D_DIM;
        const float* W2_l = W2 + (size_t)l * D_DIM * D_DIM;
        const float* b2_l = b2 + (size_t)l * D_DIM;

        if (l == 0) {
            edge_agg_csr_kernel<0><<<2048, 256, 0, stream>>>(
                xin, csr, row_off, ea, Wl_l, bl_l, nullptr, agg, N);
            gemm1_kernel<0><<<gemmBlocks, 256, 0, stream>>>(
                xin, agg, W1_l, b1_l, nullptr, h1, N);
        } else {
            edge_agg_csr_kernel<1><<<2048, 256, 0, stream>>>(
                xin, csr, row_off, ea, Wl_l, bl_l, scsh, agg, N);
            gemm1_kernel<1><<<gemmBlocks, 256, 0, stream>>>(
                xin, agg, W1_l, b1_l, scsh, h1, N);
        }

        gemm2_kernel<<<gemmBlocks, 256, 0, stream>>>(
            h1, W2_l, b2_l, out, sums, N);

        bn_finalize_kernel<<<1, 128, 0, stream>>>(
            sums, gamma + (size_t)l * D_DIM, beta + (size_t)l * D_DIM,
            scsh, 1.f / (float)N);
    }

    bn_apply_final<<<2048, 256, 0, stream>>>(out, scsh, N);
}